// Round 18
// baseline (132.322 us; speedup 1.0000x reference)
//
#include <hip/hip_runtime.h>
#include <math.h>

#define BPB 4              // bins per block in table build
#define CAP 64             // max in-degree slot capacity (deg ~ Poisson(10); P(>=64) ~ 1e-35)
static const int LBINS = 1024;   // T1+T2 = 1.75 MB -> L2-resident per XCD

__device__ __forceinline__ unsigned short f2bf(float f) {
    unsigned int u = __float_as_uint(f);
    unsigned int r = (u + 0x7FFFu + ((u >> 16) & 1u)) >> 16;   // RTN-even
    return (unsigned short)r;
}
__device__ __forceinline__ unsigned int packbf(float lo, float hi) {
    return (unsigned int)f2bf(lo) | ((unsigned int)f2bf(hi) << 16);
}
__device__ __forceinline__ float bflo(unsigned int u) { return __uint_as_float(u << 16); }
__device__ __forceinline__ float bfhi(unsigned int u) { return __uint_as_float(u & 0xFFFF0000u); }

__device__ __forceinline__ void sph_l3(float x, float y, float z, float* sh) {
    const float s3   = 1.7320508075688772f;
    const float s5   = 2.23606797749979f;
    const float s7   = 2.6457513110645906f;
    const float s15  = 3.872983346207417f;
    const float s105 = 10.246950765959598f;
    const float c358 = 2.0916500663351889f;  // sqrt(35/8)
    const float c218 = 1.6201851746019651f;  // sqrt(21/8)
    float x2 = x * x, y2 = y * y, z2 = z * z;
    sh[0]  = 1.0f;
    sh[1]  = s3 * x;
    sh[2]  = s3 * y;
    sh[3]  = s3 * z;
    sh[4]  = s15 * x * z;
    sh[5]  = s15 * x * y;
    sh[6]  = 0.5f * s5 * (2.0f * y2 - x2 - z2);
    sh[7]  = s15 * y * z;
    sh[8]  = 0.5f * s15 * (z2 - x2);
    sh[9]  = c358 * x * (3.0f * z2 - x2);
    sh[10] = s105 * x * y * z;
    sh[11] = c218 * x * (4.0f * y2 - z2 - x2);
    sh[12] = 0.5f * s7 * y * (2.0f * y2 - 3.0f * z2 - 3.0f * x2);
    sh[13] = c218 * z * (4.0f * y2 - z2 - x2);
    sh[14] = 0.5f * s105 * y * (z2 - x2);
    sh[15] = c358 * z * (z2 - 3.0f * x2);
}

__device__ __forceinline__ void unpack16(uint4 a, uint4 b, float* s) {
    s[0] = bflo(a.x);  s[1] = bfhi(a.x);  s[2] = bflo(a.y);  s[3] = bfhi(a.y);
    s[4] = bflo(a.z);  s[5] = bfhi(a.z);  s[6] = bflo(a.w);  s[7] = bfhi(a.w);
    s[8] = bflo(b.x);  s[9] = bfhi(b.x);  s[10] = bflo(b.y); s[11] = bfhi(b.y);
    s[12] = bflo(b.z); s[13] = bfhi(b.z); s[14] = bflo(b.w); s[15] = bfhi(b.w);
}

template<int STR>
__device__ __forceinline__ void gemmB(const float* __restrict__ col,
                                      const float (*__restrict__ hs)[256], float* acc) {
#pragma unroll 8
    for (int cc = 0; cc < 256; ++cc) {
        float w = col[(size_t)cc * STR];
#pragma unroll
        for (int b = 0; b < BPB; ++b) acc[b] += hs[b][cc] * w;
    }
}

// ---------------- K0: build packed tables + zero cursor ------------------------------------
__global__ __launch_bounds__(256) void k_table(const float* __restrict__ W1a,
                                               const float* __restrict__ W1b,
                                               const float* __restrict__ W2a,
                                               const float* __restrict__ W2b,
                                               unsigned int* __restrict__ T1,
                                               unsigned int* __restrict__ T2, int lbins,
                                               int* __restrict__ cursor, int N) {
    __shared__ float h1s[BPB][256];
    __shared__ float h2s[BPB][256];
    const int c = threadIdx.x;
    const int bin0 = blockIdx.x * BPB;
    const int half = blockIdx.y;

    if (half == 0) {
        int zi = blockIdx.x * 256 + c;
        if (zi < N) cursor[zi] = 0;
    }

    const float inv_s3 = 0.57735026918962576f;
    const float bin2len = 4.0f / (float)(lbins - 1);
    float w1a0 = W1a[c], w1a1 = W1a[256 + c], w1a2 = W1a[512 + c];
    float w2a0 = W2a[c], w2a1 = W2a[256 + c], w2a2 = W2a[512 + c];
#pragma unroll
    for (int b = 0; b < BPB; ++b) {
        float len = (float)(bin0 + b) * bin2len;
        float d0 = len * 0.5f;
        float d1 = (len - 2.0f) * 0.5f;
        float d2 = (len - 4.0f) * 0.5f;
        float b0 = expf(-d0 * d0) * (1.0f / 1.12f);
        float b1 = expf(-d1 * d1) * (1.0f / 1.12f);
        float b2 = expf(-d2 * d2) * (1.0f / 1.12f);
        h1s[b][c] = fmaxf((b0 * w1a0 + b1 * w1a1 + b2 * w1a2) * inv_s3, 0.0f);
        if (half == 1)
            h2s[b][c] = fmaxf((b0 * w2a0 + b1 * w2a1 + b2 * w2a2) * inv_s3, 0.0f);
    }
    __syncthreads();

    float acc[BPB];
#pragma unroll
    for (int b = 0; b < BPB; ++b) acc[b] = 0.0f;
    int o = -1;  // output column in [0,448)
    if (half == 0) {
        if (c < 224) { o = c; gemmB<384>(W1b + o, h1s, acc); }
    } else {
        if (c < 64)       { o = 384 + c; gemmB<64>(W2b + c, h2s, acc); }
        else if (c < 224) { o = 160 + c; gemmB<384>(W1b + (160 + c), h1s, acc); }
    }
    if (o >= 0) {
        unsigned short* Ts1 = (unsigned short*)T1;
        unsigned short* Ts2 = (unsigned short*)T2;
        if (o < 384) {
            int k = o % 96, pp = o / 96;
#pragma unroll
            for (int b = 0; b < BPB; ++b) {
                int i = bin0 + b;
                unsigned short hv = f2bf(acc[b] * (1.0f / 16.0f));
                Ts1[(((size_t)i * 96 + k) * 4 + pp) * 2] = hv;
                if (i > 0) Ts1[(((size_t)(i - 1) * 96 + k) * 4 + pp) * 2 + 1] = hv;
            }
        } else {
            int k2 = o - 384;
#pragma unroll
            for (int b = 0; b < BPB; ++b) {
                int i = bin0 + b;
                unsigned short hv = f2bf(acc[b] * (1.0f / 16.0f));
                Ts2[((size_t)i * 64 + k2) * 2] = hv;
                if (i > 0) Ts2[((size_t)(i - 1) * 64 + k2) * 2 + 1] = hv;
            }
        }
    }
}

// ---------------- K1: scatter edges into per-dst slot buckets ------------------------------
__global__ void k_scatter(const float* __restrict__ evec, const float* __restrict__ elen,
                          const int* __restrict__ esrc, const int* __restrict__ edst,
                          int* __restrict__ cursor,
                          uint4* __restrict__ shB4, uint2* __restrict__ edgeSL,
                          int E, int lbins) {
    int e = blockIdx.x * blockDim.x + threadIdx.x;
    if (e >= E) return;
    int d = edst[e];
    int slotIdx = atomicAdd(&cursor[d], 1);
    if (slotIdx >= CAP) return;   // statistically never
    size_t pos = ((size_t)d << 6) + slotIdx;

    float vx = evec[3 * e], vy = evec[3 * e + 1], vz = evec[3 * e + 2];
    float nrm = sqrtf(vx * vx + vy * vy + vz * vz);
    float inv = 1.0f / (nrm + 1e-12f);
    float sh[16];
    sph_l3(vx * inv, vy * inv, vz * inv, sh);
    uint4 a, b;
    a.x = packbf(sh[0], sh[1]);  a.y = packbf(sh[2], sh[3]);
    a.z = packbf(sh[4], sh[5]);  a.w = packbf(sh[6], sh[7]);
    b.x = packbf(sh[8], sh[9]);  b.y = packbf(sh[10], sh[11]);
    b.z = packbf(sh[12], sh[13]); b.w = packbf(sh[14], sh[15]);
    shB4[pos * 2]     = a;
    shB4[pos * 2 + 1] = b;

    float len = elen[e];
    float p = fminf(fmaxf(len, 0.0f), 4.0f) * ((float)(lbins - 1) / 4.0f);
    if (p > (float)(lbins - 1) - 1.0f) p = (float)(lbins - 1) - 1.0f;
    edgeSL[pos] = make_uint2((unsigned int)esrc[e], __float_as_uint(p));
}

// ---------------- K2: fused x-recompute + dots + h[96] + act -> y[n][64] -------------------
// block 128 per node (R15 form). Staging lane j recomputes x[src_j] on the fly from shB.
__global__ __launch_bounds__(128) void k_hy(const uint4* __restrict__ shB4,
                                            const uint2* __restrict__ edgeSL,
                                            const int* __restrict__ cursor,
                                            const unsigned int* __restrict__ T1,
                                            float* __restrict__ y, int N) {
    int n = blockIdx.x;
    if (n >= N) return;
    int kk = threadIdx.x;
    __shared__ float4 sdots[CAP];
    __shared__ float spos[CAP];
    __shared__ float hs[96];
    int cnt = min(cursor[n], CAP);
    size_t base = (size_t)n << 6;
    const float inv_nn = 0.51298917604257706f;
    const float rs3 = 0.57735026918962576f;
    const float rs5 = 0.44721359549995793f;
    const float rs7 = 0.37796447300922720f;

    if (kk < cnt) {
        size_t j = base + kk;
        uint2 sl = edgeSL[j];
        uint4 a = shB4[j * 2], b = shB4[j * 2 + 1];
        float s[16];
        unpack16(a, b, s);
        // recompute x[src] on the fly (identical math/order to former k_x)
        int src = (int)sl.x;
        int scnt = min(cursor[src], CAP);
        size_t sbase = (size_t)src << 6;
        float xa[16];
#pragma unroll
        for (int i = 0; i < 16; ++i) xa[i] = 0.0f;
        for (int q = 0; q < scnt; ++q) {
            uint4 sa = shB4[(sbase + q) * 2], sb = shB4[(sbase + q) * 2 + 1];
            float ss[16];
            unpack16(sa, sb, ss);
#pragma unroll
            for (int i = 0; i < 16; ++i) xa[i] += ss[i];
        }
        float d0 = xa[0] * s[0];
        float d1 = xa[1] * s[1] + xa[2] * s[2] + xa[3] * s[3];
        float d2 = xa[4] * s[4] + xa[5] * s[5] + xa[6] * s[6] + xa[7] * s[7] + xa[8] * s[8];
        float d3 = xa[9] * s[9] + xa[10] * s[10] + xa[11] * s[11]
                 + xa[12] * s[12] + xa[13] * s[13] + xa[14] * s[14] + xa[15] * s[15];
        float sc = inv_nn;
        sdots[kk] = make_float4(d0 * sc, d1 * sc * rs3, d2 * sc * rs5, d3 * sc * rs7);
        spos[kk] = __uint_as_float(sl.y);
    }
    __syncthreads();
    if (kk < 96) {
        float acc = 0.0f;
        for (int q = 0; q < cnt; ++q) {
            float4 dt = sdots[q];
            float p = spos[q];
            int i0 = (int)p;
            float f = p - (float)i0;
            uint4 u = *(const uint4*)(T1 + ((((size_t)i0 * 96) + kk) << 2));
            float a0 = bflo(u.x), b0 = bfhi(u.x);
            float a1 = bflo(u.y), b1 = bfhi(u.y);
            float a2 = bflo(u.z), b2 = bfhi(u.z);
            float a3 = bflo(u.w), b3 = bfhi(u.w);
            acc += dt.x * (a0 + f * (b0 - a0)) + dt.y * (a1 + f * (b1 - a1))
                 + dt.z * (a2 + f * (b2 - a2)) + dt.w * (a3 + f * (b3 - a3));
        }
        const float scale = 0.25649458802128853f;  // 0.5 * inv_nn
        hs[kk] = acc * scale;
    }
    __syncthreads();
    int t = threadIdx.x;
    if (t < 64) {
        float outv;
        if (t < 32) {
            float v = hs[t];
            outv = (t < 16) ? fmaxf(v, 0.0f) : fabsf(v);
        } else {
            int kg = t - 32;
            float g = hs[32 + kg];
            float vv = hs[64 + kg];
            float ga = (kg < 8 || (kg >= 16 && kg < 24)) ? fmaxf(g, 0.0f) : tanhf(g);
            outv = ga * vv;
        }
        y[(size_t)n * 64 + t] = outv;
    }
}

// ---------------- K3: out[n] = inv_nn/8 * sum_j y[src_j]·w2(pos_j)  (wave/node) -------------
__global__ void k_out(const uint2* __restrict__ edgeSL, const int* __restrict__ cursor,
                      const float* __restrict__ y,
                      const unsigned int* __restrict__ T2, float* __restrict__ out, int N) {
    int n = (blockIdx.x * blockDim.x + threadIdx.x) >> 6;
    int lane = threadIdx.x & 63;
    if (n >= N) return;
    int cnt = min(cursor[n], CAP);
    size_t base = (size_t)n << 6;
    float acc = 0.0f;
    for (int j = 0; j < cnt; ++j) {
        uint2 sl = edgeSL[base + j];
        float p = __uint_as_float(sl.y);
        int i0 = (int)p;
        float f = p - (float)i0;
        unsigned int u = T2[(size_t)i0 * 64 + lane];
        float w0 = bflo(u), w1 = bfhi(u);
        float w2v = w0 + f * (w1 - w0);
        acc += y[(size_t)sl.x * 64 + lane] * w2v;
    }
#pragma unroll
    for (int off = 32; off > 0; off >>= 1) acc += __shfl_xor(acc, off, 64);
    if (lane == 0) out[n] = acc * (0.51298917604257706f / 8.0f);
}

extern "C" void kernel_launch(void* const* d_in, const int* in_sizes, int n_in,
                              void* d_out, int out_size, void* d_ws, size_t ws_size,
                              hipStream_t stream) {
    const float* evec = (const float*)d_in[0];
    const float* elen = (const float*)d_in[1];
    const float* W1a  = (const float*)d_in[2];
    const float* W1b  = (const float*)d_in[3];
    const float* W2a  = (const float*)d_in[4];
    const float* W2b  = (const float*)d_in[5];
    const int* esrc   = (const int*)d_in[6];
    const int* edst   = (const int*)d_in[7];
    const int E = in_sizes[1];
    const int N = out_size;
    float* out = (float*)d_out;

    char* ws = (char*)d_ws;
    size_t off = 0;
    auto alloc = [&](size_t bytes) -> void* {
        void* p = ws + off;
        off = (off + bytes + 255) & ~(size_t)255;
        return p;
    };

    int*    cursor = (int*)alloc((size_t)N * 4);
    uint4*  shB4   = (uint4*)alloc((size_t)N * CAP * 32);
    uint2*  edgeSL = (uint2*)alloc((size_t)N * CAP * 8);
    float*  y      = (float*)alloc((size_t)N * 64 * 4);

    int lbins = LBINS;
    if (ws_size > off) {
        size_t avail = ws_size - off;
        size_t maxbins = avail / (96 * 16 + 64 * 4);   // bytes per bin: T1 + T2
        if ((size_t)lbins > maxbins) lbins = (int)((maxbins / BPB) * BPB);
    }
    if (lbins < 2 * BPB) lbins = 2 * BPB;
    unsigned int* T1 = (unsigned int*)alloc((size_t)lbins * 96 * 16);
    unsigned int* T2 = (unsigned int*)alloc((size_t)lbins * 64 * 4);

    k_table<<<dim3(lbins / BPB, 2), 256, 0, stream>>>(W1a, W1b, W2a, W2b, T1, T2, lbins,
                                                      cursor, N);
    k_scatter<<<(E + 255) / 256, 256, 0, stream>>>(evec, elen, esrc, edst, cursor,
                                                   shB4, edgeSL, E, lbins);
    k_hy<<<N, 128, 0, stream>>>(shB4, edgeSL, cursor, T1, y, N);
    {
        long long threads = (long long)N * 64;
        int blocks = (int)((threads + 255) / 256);
        k_out<<<blocks, 256, 0, stream>>>(edgeSL, cursor, y, T2, out, N);
    }
}

// Round 19
// 92.010 us; speedup vs baseline: 1.4381x; 1.4381x over previous
//
#include <hip/hip_runtime.h>
#include <math.h>

#define BPB 4              // bins per block in table build
#define CAP 64             // max in-degree slot capacity (deg ~ Poisson(10); P(>=64) ~ 1e-35)
static const int LBINS = 1024;   // T1+T2 = 1.75 MB -> L2-resident per XCD

__device__ __forceinline__ unsigned short f2bf(float f) {
    unsigned int u = __float_as_uint(f);
    unsigned int r = (u + 0x7FFFu + ((u >> 16) & 1u)) >> 16;   // RTN-even
    return (unsigned short)r;
}
__device__ __forceinline__ unsigned int packbf(float lo, float hi) {
    return (unsigned int)f2bf(lo) | ((unsigned int)f2bf(hi) << 16);
}
__device__ __forceinline__ float bflo(unsigned int u) { return __uint_as_float(u << 16); }
__device__ __forceinline__ float bfhi(unsigned int u) { return __uint_as_float(u & 0xFFFF0000u); }

__device__ __forceinline__ void sph_l3(float x, float y, float z, float* sh) {
    const float s3   = 1.7320508075688772f;
    const float s5   = 2.23606797749979f;
    const float s7   = 2.6457513110645906f;
    const float s15  = 3.872983346207417f;
    const float s105 = 10.246950765959598f;
    const float c358 = 2.0916500663351889f;  // sqrt(35/8)
    const float c218 = 1.6201851746019651f;  // sqrt(21/8)
    float x2 = x * x, y2 = y * y, z2 = z * z;
    sh[0]  = 1.0f;
    sh[1]  = s3 * x;
    sh[2]  = s3 * y;
    sh[3]  = s3 * z;
    sh[4]  = s15 * x * z;
    sh[5]  = s15 * x * y;
    sh[6]  = 0.5f * s5 * (2.0f * y2 - x2 - z2);
    sh[7]  = s15 * y * z;
    sh[8]  = 0.5f * s15 * (z2 - x2);
    sh[9]  = c358 * x * (3.0f * z2 - x2);
    sh[10] = s105 * x * y * z;
    sh[11] = c218 * x * (4.0f * y2 - z2 - x2);
    sh[12] = 0.5f * s7 * y * (2.0f * y2 - 3.0f * z2 - 3.0f * x2);
    sh[13] = c218 * z * (4.0f * y2 - z2 - x2);
    sh[14] = 0.5f * s105 * y * (z2 - x2);
    sh[15] = c358 * z * (z2 - 3.0f * x2);
}

__device__ __forceinline__ void unpack16(uint4 a, uint4 b, float* s) {
    s[0] = bflo(a.x);  s[1] = bfhi(a.x);  s[2] = bflo(a.y);  s[3] = bfhi(a.y);
    s[4] = bflo(a.z);  s[5] = bfhi(a.z);  s[6] = bflo(a.w);  s[7] = bfhi(a.w);
    s[8] = bflo(b.x);  s[9] = bfhi(b.x);  s[10] = bflo(b.y); s[11] = bfhi(b.y);
    s[12] = bflo(b.z); s[13] = bfhi(b.z); s[14] = bflo(b.w); s[15] = bfhi(b.w);
}

template<int STR>
__device__ __forceinline__ void gemmB(const float* __restrict__ col,
                                      const float (*__restrict__ hs)[256], float* acc) {
#pragma unroll 8
    for (int cc = 0; cc < 256; ++cc) {
        float w = col[(size_t)cc * STR];
#pragma unroll
        for (int b = 0; b < BPB; ++b) acc[b] += hs[b][cc] * w;
    }
}

// ---------------- K0: build packed tables + zero cursor ------------------------------------
__global__ __launch_bounds__(256) void k_table(const float* __restrict__ W1a,
                                               const float* __restrict__ W1b,
                                               const float* __restrict__ W2a,
                                               const float* __restrict__ W2b,
                                               unsigned int* __restrict__ T1,
                                               unsigned int* __restrict__ T2, int lbins,
                                               int* __restrict__ cursor, int N) {
    __shared__ float h1s[BPB][256];
    __shared__ float h2s[BPB][256];
    const int c = threadIdx.x;
    const int bin0 = blockIdx.x * BPB;
    const int half = blockIdx.y;

    if (half == 0) {
        int zi = blockIdx.x * 256 + c;
        if (zi < N) cursor[zi] = 0;
    }

    const float inv_s3 = 0.57735026918962576f;
    const float bin2len = 4.0f / (float)(lbins - 1);
    float w1a0 = W1a[c], w1a1 = W1a[256 + c], w1a2 = W1a[512 + c];
    float w2a0 = W2a[c], w2a1 = W2a[256 + c], w2a2 = W2a[512 + c];
#pragma unroll
    for (int b = 0; b < BPB; ++b) {
        float len = (float)(bin0 + b) * bin2len;
        float d0 = len * 0.5f;
        float d1 = (len - 2.0f) * 0.5f;
        float d2 = (len - 4.0f) * 0.5f;
        float b0 = expf(-d0 * d0) * (1.0f / 1.12f);
        float b1 = expf(-d1 * d1) * (1.0f / 1.12f);
        float b2 = expf(-d2 * d2) * (1.0f / 1.12f);
        h1s[b][c] = fmaxf((b0 * w1a0 + b1 * w1a1 + b2 * w1a2) * inv_s3, 0.0f);
        if (half == 1)
            h2s[b][c] = fmaxf((b0 * w2a0 + b1 * w2a1 + b2 * w2a2) * inv_s3, 0.0f);
    }
    __syncthreads();

    float acc[BPB];
#pragma unroll
    for (int b = 0; b < BPB; ++b) acc[b] = 0.0f;
    int o = -1;  // output column in [0,448)
    if (half == 0) {
        if (c < 224) { o = c; gemmB<384>(W1b + o, h1s, acc); }
    } else {
        if (c < 64)       { o = 384 + c; gemmB<64>(W2b + c, h2s, acc); }
        else if (c < 224) { o = 160 + c; gemmB<384>(W1b + (160 + c), h1s, acc); }
    }
    if (o >= 0) {
        unsigned short* Ts1 = (unsigned short*)T1;
        unsigned short* Ts2 = (unsigned short*)T2;
        if (o < 384) {
            int k = o % 96, pp = o / 96;
#pragma unroll
            for (int b = 0; b < BPB; ++b) {
                int i = bin0 + b;
                unsigned short hv = f2bf(acc[b] * (1.0f / 16.0f));
                Ts1[(((size_t)i * 96 + k) * 4 + pp) * 2] = hv;
                if (i > 0) Ts1[(((size_t)(i - 1) * 96 + k) * 4 + pp) * 2 + 1] = hv;
            }
        } else {
            int k2 = o - 384;
#pragma unroll
            for (int b = 0; b < BPB; ++b) {
                int i = bin0 + b;
                unsigned short hv = f2bf(acc[b] * (1.0f / 16.0f));
                Ts2[((size_t)i * 64 + k2) * 2] = hv;
                if (i > 0) Ts2[((size_t)(i - 1) * 64 + k2) * 2 + 1] = hv;
            }
        }
    }
}

// ---------------- K1: scatter edges into per-dst slot buckets ------------------------------
__global__ void k_scatter(const float* __restrict__ evec, const float* __restrict__ elen,
                          const int* __restrict__ esrc, const int* __restrict__ edst,
                          int* __restrict__ cursor,
                          uint4* __restrict__ shB4, uint2* __restrict__ edgeSL,
                          int E, int lbins) {
    int e = blockIdx.x * blockDim.x + threadIdx.x;
    if (e >= E) return;
    int d = edst[e];
    int slotIdx = atomicAdd(&cursor[d], 1);
    if (slotIdx >= CAP) return;   // statistically never
    size_t pos = ((size_t)d << 6) + slotIdx;

    float vx = evec[3 * e], vy = evec[3 * e + 1], vz = evec[3 * e + 2];
    float nrm = sqrtf(vx * vx + vy * vy + vz * vz);
    float inv = 1.0f / (nrm + 1e-12f);
    float sh[16];
    sph_l3(vx * inv, vy * inv, vz * inv, sh);
    uint4 a, b;
    a.x = packbf(sh[0], sh[1]);  a.y = packbf(sh[2], sh[3]);
    a.z = packbf(sh[4], sh[5]);  a.w = packbf(sh[6], sh[7]);
    b.x = packbf(sh[8], sh[9]);  b.y = packbf(sh[10], sh[11]);
    b.z = packbf(sh[12], sh[13]); b.w = packbf(sh[14], sh[15]);
    shB4[pos * 2]     = a;
    shB4[pos * 2 + 1] = b;

    float len = elen[e];
    float p = fminf(fmaxf(len, 0.0f), 4.0f) * ((float)(lbins - 1) / 4.0f);
    if (p > (float)(lbins - 1) - 1.0f) p = (float)(lbins - 1) - 1.0f;
    edgeSL[pos] = make_uint2((unsigned int)esrc[e], __float_as_uint(p));
}

// ---------------- K2: x[n][16] = inv_nn * sum of node's slot rows (thread per node) --------
__global__ void k_x(const uint4* __restrict__ shB4, const int* __restrict__ cursor,
                    float4* __restrict__ x4, int N) {
    int n = blockIdx.x * blockDim.x + threadIdx.x;
    if (n >= N) return;
    float acc[16];
#pragma unroll
    for (int i = 0; i < 16; ++i) acc[i] = 0.0f;
    int cnt = min(cursor[n], CAP);
    size_t base = (size_t)n << 6;
    for (int j = 0; j < cnt; ++j) {
        uint4 a = shB4[(base + j) * 2], b = shB4[(base + j) * 2 + 1];
        float s[16];
        unpack16(a, b, s);
#pragma unroll
        for (int i = 0; i < 16; ++i) acc[i] += s[i];
    }
    const float inv_nn = 0.51298917604257706f;
    float4* xp = x4 + (size_t)n * 4;
    xp[0] = make_float4(acc[0] * inv_nn, acc[1] * inv_nn, acc[2] * inv_nn, acc[3] * inv_nn);
    xp[1] = make_float4(acc[4] * inv_nn, acc[5] * inv_nn, acc[6] * inv_nn, acc[7] * inv_nn);
    xp[2] = make_float4(acc[8] * inv_nn, acc[9] * inv_nn, acc[10] * inv_nn, acc[11] * inv_nn);
    xp[3] = make_float4(acc[12] * inv_nn, acc[13] * inv_nn, acc[14] * inv_nn, acc[15] * inv_nn);
}

// ---------------- K3: fused dots + h[96] + activations -> y[n][64]  (block 128 per node) ---
__global__ __launch_bounds__(128) void k_hy(const uint4* __restrict__ shB4,
                                            const uint2* __restrict__ edgeSL,
                                            const int* __restrict__ cursor,
                                            const float4* __restrict__ x4,
                                            const unsigned int* __restrict__ T1,
                                            float* __restrict__ y, int N) {
    int n = blockIdx.x;
    if (n >= N) return;
    int kk = threadIdx.x;
    __shared__ float4 sdots[CAP];
    __shared__ float spos[CAP];
    __shared__ float hs[96];
    int cnt = min(cursor[n], CAP);
    size_t base = (size_t)n << 6;
    const float rs3 = 0.57735026918962576f;
    const float rs5 = 0.44721359549995793f;
    const float rs7 = 0.37796447300922720f;

    if (kk < cnt) {
        size_t j = base + kk;
        uint2 sl = edgeSL[j];
        uint4 a = shB4[j * 2], b = shB4[j * 2 + 1];
        float s[16];
        unpack16(a, b, s);
        const float4* xr = x4 + (size_t)sl.x * 4;
        float4 x0 = xr[0], x1 = xr[1], x2 = xr[2], x3 = xr[3];
        float d0 = x0.x * s[0];
        float d1 = x0.y * s[1] + x0.z * s[2] + x0.w * s[3];
        float d2 = x1.x * s[4] + x1.y * s[5] + x1.z * s[6] + x1.w * s[7] + x2.x * s[8];
        float d3 = x2.y * s[9] + x2.z * s[10] + x2.w * s[11]
                 + x3.x * s[12] + x3.y * s[13] + x3.z * s[14] + x3.w * s[15];
        sdots[kk] = make_float4(d0, d1 * rs3, d2 * rs5, d3 * rs7);
        spos[kk] = __uint_as_float(sl.y);
    }
    __syncthreads();
    if (kk < 96) {
        float acc = 0.0f;
#pragma unroll 4
        for (int q = 0; q < cnt; ++q) {
            float4 dt = sdots[q];
            float p = spos[q];
            int i0 = (int)p;
            float f = p - (float)i0;
            uint4 u = *(const uint4*)(T1 + ((((size_t)i0 * 96) + kk) << 2));
            float a0 = bflo(u.x), b0 = bfhi(u.x);
            float a1 = bflo(u.y), b1 = bfhi(u.y);
            float a2 = bflo(u.z), b2 = bfhi(u.z);
            float a3 = bflo(u.w), b3 = bfhi(u.w);
            acc += dt.x * (a0 + f * (b0 - a0)) + dt.y * (a1 + f * (b1 - a1))
                 + dt.z * (a2 + f * (b2 - a2)) + dt.w * (a3 + f * (b3 - a3));
        }
        const float scale = 0.25649458802128853f;  // 0.5 * inv_nn
        hs[kk] = acc * scale;
    }
    __syncthreads();
    int t = threadIdx.x;
    if (t < 64) {
        float outv;
        if (t < 32) {
            float v = hs[t];
            outv = (t < 16) ? fmaxf(v, 0.0f) : fabsf(v);
        } else {
            int kg = t - 32;
            float g = hs[32 + kg];
            float vv = hs[64 + kg];
            float ga = (kg < 8 || (kg >= 16 && kg < 24)) ? fmaxf(g, 0.0f) : tanhf(g);
            outv = ga * vv;
        }
        y[(size_t)n * 64 + t] = outv;
    }
}

// ---------------- K4: out[n] = inv_nn/8 * sum_j y[src_j]·w2(pos_j)  (wave/node) -------------
__global__ void k_out(const uint2* __restrict__ edgeSL, const int* __restrict__ cursor,
                      const float* __restrict__ y,
                      const unsigned int* __restrict__ T2, float* __restrict__ out, int N) {
    int n = (blockIdx.x * blockDim.x + threadIdx.x) >> 6;
    int lane = threadIdx.x & 63;
    if (n >= N) return;
    int cnt = min(cursor[n], CAP);
    size_t base = (size_t)n << 6;
    float acc = 0.0f;
#pragma unroll 4
    for (int j = 0; j < cnt; ++j) {
        uint2 sl = edgeSL[base + j];
        float p = __uint_as_float(sl.y);
        int i0 = (int)p;
        float f = p - (float)i0;
        unsigned int u = T2[(size_t)i0 * 64 + lane];
        float w0 = bflo(u), w1 = bfhi(u);
        float w2v = w0 + f * (w1 - w0);
        acc += y[(size_t)sl.x * 64 + lane] * w2v;
    }
#pragma unroll
    for (int off = 32; off > 0; off >>= 1) acc += __shfl_xor(acc, off, 64);
    if (lane == 0) out[n] = acc * (0.51298917604257706f / 8.0f);
}

extern "C" void kernel_launch(void* const* d_in, const int* in_sizes, int n_in,
                              void* d_out, int out_size, void* d_ws, size_t ws_size,
                              hipStream_t stream) {
    const float* evec = (const float*)d_in[0];
    const float* elen = (const float*)d_in[1];
    const float* W1a  = (const float*)d_in[2];
    const float* W1b  = (const float*)d_in[3];
    const float* W2a  = (const float*)d_in[4];
    const float* W2b  = (const float*)d_in[5];
    const int* esrc   = (const int*)d_in[6];
    const int* edst   = (const int*)d_in[7];
    const int E = in_sizes[1];
    const int N = out_size;
    float* out = (float*)d_out;

    char* ws = (char*)d_ws;
    size_t off = 0;
    auto alloc = [&](size_t bytes) -> void* {
        void* p = ws + off;
        off = (off + bytes + 255) & ~(size_t)255;
        return p;
    };

    int*    cursor = (int*)alloc((size_t)N * 4);
    uint4*  shB4   = (uint4*)alloc((size_t)N * CAP * 32);
    uint2*  edgeSL = (uint2*)alloc((size_t)N * CAP * 8);
    float4* x4     = (float4*)alloc((size_t)N * 64);
    float*  y      = (float*)alloc((size_t)N * 64 * 4);

    int lbins = LBINS;
    if (ws_size > off) {
        size_t avail = ws_size - off;
        size_t maxbins = avail / (96 * 16 + 64 * 4);   // bytes per bin: T1 + T2
        if ((size_t)lbins > maxbins) lbins = (int)((maxbins / BPB) * BPB);
    }
    if (lbins < 2 * BPB) lbins = 2 * BPB;
    unsigned int* T1 = (unsigned int*)alloc((size_t)lbins * 96 * 16);
    unsigned int* T2 = (unsigned int*)alloc((size_t)lbins * 64 * 4);

    k_table<<<dim3(lbins / BPB, 2), 256, 0, stream>>>(W1a, W1b, W2a, W2b, T1, T2, lbins,
                                                      cursor, N);
    k_scatter<<<(E + 255) / 256, 256, 0, stream>>>(evec, elen, esrc, edst, cursor,
                                                   shB4, edgeSL, E, lbins);
    k_x<<<(N + 255) / 256, 256, 0, stream>>>(shB4, cursor, x4, N);
    k_hy<<<N, 128, 0, stream>>>(shB4, edgeSL, cursor, x4, T1, y, N);
    {
        long long threads = (long long)N * 64;
        int blocks = (int)((threads + 255) / 256);
        k_out<<<blocks, 256, 0, stream>>>(edgeSL, cursor, y, T2, out, N);
    }
}

// Round 20
// 89.830 us; speedup vs baseline: 1.4730x; 1.0243x over previous
//
#include <hip/hip_runtime.h>
#include <math.h>

#define BPB 4              // bins per block in table build
#define CAP 64             // max in-degree slot capacity (deg ~ Poisson(10); P(>=64) ~ 1e-35)
static const int LBINS = 2048;   // nearest-neighbor tables: T1=1.5MB + T2=256KB -> L2-resident

__device__ __forceinline__ unsigned short f2bf(float f) {
    unsigned int u = __float_as_uint(f);
    unsigned int r = (u + 0x7FFFu + ((u >> 16) & 1u)) >> 16;   // RTN-even
    return (unsigned short)r;
}
__device__ __forceinline__ unsigned int packbf(float lo, float hi) {
    return (unsigned int)f2bf(lo) | ((unsigned int)f2bf(hi) << 16);
}
__device__ __forceinline__ float bflo(unsigned int u) { return __uint_as_float(u << 16); }
__device__ __forceinline__ float bfhi(unsigned int u) { return __uint_as_float(u & 0xFFFF0000u); }
__device__ __forceinline__ float bfu16(unsigned short u) { return __uint_as_float(((unsigned int)u) << 16); }

__device__ __forceinline__ void sph_l3(float x, float y, float z, float* sh) {
    const float s3   = 1.7320508075688772f;
    const float s5   = 2.23606797749979f;
    const float s7   = 2.6457513110645906f;
    const float s15  = 3.872983346207417f;
    const float s105 = 10.246950765959598f;
    const float c358 = 2.0916500663351889f;  // sqrt(35/8)
    const float c218 = 1.6201851746019651f;  // sqrt(21/8)
    float x2 = x * x, y2 = y * y, z2 = z * z;
    sh[0]  = 1.0f;
    sh[1]  = s3 * x;
    sh[2]  = s3 * y;
    sh[3]  = s3 * z;
    sh[4]  = s15 * x * z;
    sh[5]  = s15 * x * y;
    sh[6]  = 0.5f * s5 * (2.0f * y2 - x2 - z2);
    sh[7]  = s15 * y * z;
    sh[8]  = 0.5f * s15 * (z2 - x2);
    sh[9]  = c358 * x * (3.0f * z2 - x2);
    sh[10] = s105 * x * y * z;
    sh[11] = c218 * x * (4.0f * y2 - z2 - x2);
    sh[12] = 0.5f * s7 * y * (2.0f * y2 - 3.0f * z2 - 3.0f * x2);
    sh[13] = c218 * z * (4.0f * y2 - z2 - x2);
    sh[14] = 0.5f * s105 * y * (z2 - x2);
    sh[15] = c358 * z * (z2 - 3.0f * x2);
}

__device__ __forceinline__ void unpack16(uint4 a, uint4 b, float* s) {
    s[0] = bflo(a.x);  s[1] = bfhi(a.x);  s[2] = bflo(a.y);  s[3] = bfhi(a.y);
    s[4] = bflo(a.z);  s[5] = bfhi(a.z);  s[6] = bflo(a.w);  s[7] = bfhi(a.w);
    s[8] = bflo(b.x);  s[9] = bfhi(b.x);  s[10] = bflo(b.y); s[11] = bfhi(b.y);
    s[12] = bflo(b.z); s[13] = bfhi(b.z); s[14] = bflo(b.w); s[15] = bfhi(b.w);
}

template<int STR>
__device__ __forceinline__ void gemmB(const float* __restrict__ col,
                                      const float (*__restrict__ hs)[256], float* acc) {
#pragma unroll 8
    for (int cc = 0; cc < 256; ++cc) {
        float w = col[(size_t)cc * STR];
#pragma unroll
        for (int b = 0; b < BPB; ++b) acc[b] += hs[b][cc] * w;
    }
}

// ---------------- K0: build nearest-neighbor tables + zero cursor --------------------------
// T1 (ushort): [(i*96+k)*4 + p] = bf16( w1(len_i)[p*96+k] / 16 )   -> uint2 row per (i,k)
// T2 (ushort): [i*64+k2]        = bf16( w2(len_i)[k2] / 16 )
__global__ __launch_bounds__(256) void k_table(const float* __restrict__ W1a,
                                               const float* __restrict__ W1b,
                                               const float* __restrict__ W2a,
                                               const float* __restrict__ W2b,
                                               unsigned short* __restrict__ T1,
                                               unsigned short* __restrict__ T2, int lbins,
                                               int* __restrict__ cursor, int N) {
    __shared__ float h1s[BPB][256];
    __shared__ float h2s[BPB][256];
    const int c = threadIdx.x;
    const int bin0 = blockIdx.x * BPB;
    const int half = blockIdx.y;

    if (half == 0) {
        int zi = blockIdx.x * 256 + c;
        if (zi < N) cursor[zi] = 0;
    }

    const float inv_s3 = 0.57735026918962576f;
    const float bin2len = 4.0f / (float)(lbins - 1);
    float w1a0 = W1a[c], w1a1 = W1a[256 + c], w1a2 = W1a[512 + c];
    float w2a0 = W2a[c], w2a1 = W2a[256 + c], w2a2 = W2a[512 + c];
#pragma unroll
    for (int b = 0; b < BPB; ++b) {
        float len = (float)(bin0 + b) * bin2len;
        float d0 = len * 0.5f;
        float d1 = (len - 2.0f) * 0.5f;
        float d2 = (len - 4.0f) * 0.5f;
        float b0 = expf(-d0 * d0) * (1.0f / 1.12f);
        float b1 = expf(-d1 * d1) * (1.0f / 1.12f);
        float b2 = expf(-d2 * d2) * (1.0f / 1.12f);
        h1s[b][c] = fmaxf((b0 * w1a0 + b1 * w1a1 + b2 * w1a2) * inv_s3, 0.0f);
        if (half == 1)
            h2s[b][c] = fmaxf((b0 * w2a0 + b1 * w2a1 + b2 * w2a2) * inv_s3, 0.0f);
    }
    __syncthreads();

    float acc[BPB];
#pragma unroll
    for (int b = 0; b < BPB; ++b) acc[b] = 0.0f;
    int o = -1;  // output column in [0,448)
    if (half == 0) {
        if (c < 224) { o = c; gemmB<384>(W1b + o, h1s, acc); }
    } else {
        if (c < 64)       { o = 384 + c; gemmB<64>(W2b + c, h2s, acc); }
        else if (c < 224) { o = 160 + c; gemmB<384>(W1b + (160 + c), h1s, acc); }
    }
    if (o >= 0) {
        if (o < 384) {
            int k = o % 96, pp = o / 96;
#pragma unroll
            for (int b = 0; b < BPB; ++b) {
                int i = bin0 + b;
                T1[(((size_t)i * 96 + k) << 2) + pp] = f2bf(acc[b] * (1.0f / 16.0f));
            }
        } else {
            int k2 = o - 384;
#pragma unroll
            for (int b = 0; b < BPB; ++b) {
                int i = bin0 + b;
                T2[(size_t)i * 64 + k2] = f2bf(acc[b] * (1.0f / 16.0f));
            }
        }
    }
}

// ---------------- K1: scatter edges into per-dst slot buckets ------------------------------
__global__ void k_scatter(const float* __restrict__ evec, const float* __restrict__ elen,
                          const int* __restrict__ esrc, const int* __restrict__ edst,
                          int* __restrict__ cursor,
                          uint4* __restrict__ shB4, uint2* __restrict__ edgeSL,
                          int E, int lbins) {
    int e = blockIdx.x * blockDim.x + threadIdx.x;
    if (e >= E) return;
    int d = edst[e];
    int slotIdx = atomicAdd(&cursor[d], 1);
    if (slotIdx >= CAP) return;   // statistically never
    size_t pos = ((size_t)d << 6) + slotIdx;

    float vx = evec[3 * e], vy = evec[3 * e + 1], vz = evec[3 * e + 2];
    float nrm = sqrtf(vx * vx + vy * vy + vz * vz);
    float inv = 1.0f / (nrm + 1e-12f);
    float sh[16];
    sph_l3(vx * inv, vy * inv, vz * inv, sh);
    uint4 a, b;
    a.x = packbf(sh[0], sh[1]);  a.y = packbf(sh[2], sh[3]);
    a.z = packbf(sh[4], sh[5]);  a.w = packbf(sh[6], sh[7]);
    b.x = packbf(sh[8], sh[9]);  b.y = packbf(sh[10], sh[11]);
    b.z = packbf(sh[12], sh[13]); b.w = packbf(sh[14], sh[15]);
    shB4[pos * 2]     = a;
    shB4[pos * 2 + 1] = b;

    float len = elen[e];
    float p = fminf(fmaxf(len, 0.0f), 4.0f) * ((float)(lbins - 1) / 4.0f);
    int i0 = (int)(p + 0.5f);                  // nearest bin
    if (i0 > lbins - 1) i0 = lbins - 1;
    edgeSL[pos] = make_uint2((unsigned int)esrc[e], (unsigned int)i0);
}

// ---------------- K2: x[n][16] = inv_nn * sum of node's slot rows (thread per node) --------
__global__ void k_x(const uint4* __restrict__ shB4, const int* __restrict__ cursor,
                    float4* __restrict__ x4, int N) {
    int n = blockIdx.x * blockDim.x + threadIdx.x;
    if (n >= N) return;
    float acc[16];
#pragma unroll
    for (int i = 0; i < 16; ++i) acc[i] = 0.0f;
    int cnt = min(cursor[n], CAP);
    size_t base = (size_t)n << 6;
    for (int j = 0; j < cnt; ++j) {
        uint4 a = shB4[(base + j) * 2], b = shB4[(base + j) * 2 + 1];
        float s[16];
        unpack16(a, b, s);
#pragma unroll
        for (int i = 0; i < 16; ++i) acc[i] += s[i];
    }
    const float inv_nn = 0.51298917604257706f;
    float4* xp = x4 + (size_t)n * 4;
    xp[0] = make_float4(acc[0] * inv_nn, acc[1] * inv_nn, acc[2] * inv_nn, acc[3] * inv_nn);
    xp[1] = make_float4(acc[4] * inv_nn, acc[5] * inv_nn, acc[6] * inv_nn, acc[7] * inv_nn);
    xp[2] = make_float4(acc[8] * inv_nn, acc[9] * inv_nn, acc[10] * inv_nn, acc[11] * inv_nn);
    xp[3] = make_float4(acc[12] * inv_nn, acc[13] * inv_nn, acc[14] * inv_nn, acc[15] * inv_nn);
}

// ---------------- K3: fused dots + h[96] + activations -> y[n][64]  (block 128 per node) ---
__global__ __launch_bounds__(128) void k_hy(const uint4* __restrict__ shB4,
                                            const uint2* __restrict__ edgeSL,
                                            const int* __restrict__ cursor,
                                            const float4* __restrict__ x4,
                                            const uint2* __restrict__ T1v,
                                            float* __restrict__ y, int N) {
    int n = blockIdx.x;
    if (n >= N) return;
    int kk = threadIdx.x;
    __shared__ float4 sdots[CAP];
    __shared__ int sbin[CAP];
    __shared__ float hs[96];
    int cnt = min(cursor[n], CAP);
    size_t base = (size_t)n << 6;
    const float rs3 = 0.57735026918962576f;
    const float rs5 = 0.44721359549995793f;
    const float rs7 = 0.37796447300922720f;

    if (kk < cnt) {
        size_t j = base + kk;
        uint2 sl = edgeSL[j];
        uint4 a = shB4[j * 2], b = shB4[j * 2 + 1];
        float s[16];
        unpack16(a, b, s);
        const float4* xr = x4 + (size_t)sl.x * 4;
        float4 x0 = xr[0], x1 = xr[1], x2 = xr[2], x3 = xr[3];
        float d0 = x0.x * s[0];
        float d1 = x0.y * s[1] + x0.z * s[2] + x0.w * s[3];
        float d2 = x1.x * s[4] + x1.y * s[5] + x1.z * s[6] + x1.w * s[7] + x2.x * s[8];
        float d3 = x2.y * s[9] + x2.z * s[10] + x2.w * s[11]
                 + x3.x * s[12] + x3.y * s[13] + x3.z * s[14] + x3.w * s[15];
        sdots[kk] = make_float4(d0, d1 * rs3, d2 * rs5, d3 * rs7);
        sbin[kk] = (int)sl.y;
    }
    __syncthreads();
    if (kk < 96) {
        float acc = 0.0f;
#pragma unroll 4
        for (int q = 0; q < cnt; ++q) {
            float4 dt = sdots[q];
            int i0 = sbin[q];
            uint2 u = T1v[(size_t)i0 * 96 + kk];
            acc += dt.x * bflo(u.x) + dt.y * bfhi(u.x)
                 + dt.z * bflo(u.y) + dt.w * bfhi(u.y);
        }
        const float scale = 0.25649458802128853f;  // 0.5 * inv_nn
        hs[kk] = acc * scale;
    }
    __syncthreads();
    int t = threadIdx.x;
    if (t < 64) {
        float outv;
        if (t < 32) {
            float v = hs[t];
            outv = (t < 16) ? fmaxf(v, 0.0f) : fabsf(v);
        } else {
            int kg = t - 32;
            float g = hs[32 + kg];
            float vv = hs[64 + kg];
            float ga = (kg < 8 || (kg >= 16 && kg < 24)) ? fmaxf(g, 0.0f) : tanhf(g);
            outv = ga * vv;
        }
        y[(size_t)n * 64 + t] = outv;
    }
}

// ---------------- K4: out[n] = inv_nn/8 * sum_j y[src_j]·w2(bin_j)  (wave/node) -------------
__global__ void k_out(const uint2* __restrict__ edgeSL, const int* __restrict__ cursor,
                      const float* __restrict__ y,
                      const unsigned short* __restrict__ T2, float* __restrict__ out, int N) {
    int n = (blockIdx.x * blockDim.x + threadIdx.x) >> 6;
    int lane = threadIdx.x & 63;
    if (n >= N) return;
    int cnt = min(cursor[n], CAP);
    size_t base = (size_t)n << 6;
    float acc = 0.0f;
#pragma unroll 4
    for (int j = 0; j < cnt; ++j) {
        uint2 sl = edgeSL[base + j];
        float w2v = bfu16(T2[(size_t)sl.y * 64 + lane]);
        acc += y[(size_t)sl.x * 64 + lane] * w2v;
    }
#pragma unroll
    for (int off = 32; off > 0; off >>= 1) acc += __shfl_xor(acc, off, 64);
    if (lane == 0) out[n] = acc * (0.51298917604257706f / 8.0f);
}

extern "C" void kernel_launch(void* const* d_in, const int* in_sizes, int n_in,
                              void* d_out, int out_size, void* d_ws, size_t ws_size,
                              hipStream_t stream) {
    const float* evec = (const float*)d_in[0];
    const float* elen = (const float*)d_in[1];
    const float* W1a  = (const float*)d_in[2];
    const float* W1b  = (const float*)d_in[3];
    const float* W2a  = (const float*)d_in[4];
    const float* W2b  = (const float*)d_in[5];
    const int* esrc   = (const int*)d_in[6];
    const int* edst   = (const int*)d_in[7];
    const int E = in_sizes[1];
    const int N = out_size;
    float* out = (float*)d_out;

    char* ws = (char*)d_ws;
    size_t off = 0;
    auto alloc = [&](size_t bytes) -> void* {
        void* p = ws + off;
        off = (off + bytes + 255) & ~(size_t)255;
        return p;
    };

    int*    cursor = (int*)alloc((size_t)N * 4);
    uint4*  shB4   = (uint4*)alloc((size_t)N * CAP * 32);
    uint2*  edgeSL = (uint2*)alloc((size_t)N * CAP * 8);
    float4* x4     = (float4*)alloc((size_t)N * 64);
    float*  y      = (float*)alloc((size_t)N * 64 * 4);

    int lbins = LBINS;
    if (ws_size > off) {
        size_t avail = ws_size - off;
        size_t maxbins = avail / (96 * 8 + 64 * 2);   // bytes per bin: T1 + T2 (nearest)
        if ((size_t)lbins > maxbins) lbins = (int)((maxbins / BPB) * BPB);
    }
    if (lbins < 2 * BPB) lbins = 2 * BPB;
    unsigned short* T1 = (unsigned short*)alloc((size_t)lbins * 96 * 8);
    unsigned short* T2 = (unsigned short*)alloc((size_t)lbins * 64 * 2);

    k_table<<<dim3(lbins / BPB, 2), 256, 0, stream>>>(W1a, W1b, W2a, W2b, T1, T2, lbins,
                                                      cursor, N);
    k_scatter<<<(E + 255) / 256, 256, 0, stream>>>(evec, elen, esrc, edst, cursor,
                                                   shB4, edgeSL, E, lbins);
    k_x<<<(N + 255) / 256, 256, 0, stream>>>(shB4, cursor, x4, N);
    k_hy<<<N, 128, 0, stream>>>(shB4, edgeSL, cursor, x4, (const uint2*)T1, y, N);
    {
        long long threads = (long long)N * 64;
        int blocks = (int)((threads + 255) / 256);
        k_out<<<blocks, 256, 0, stream>>>(edgeSL, cursor, y, T2, out, N);
    }
}

// Round 21
// 89.162 us; speedup vs baseline: 1.4841x; 1.0075x over previous
//
#include <hip/hip_runtime.h>
#include <math.h>

#define BPB 4              // bins per block in table build
#define CAP 64             // max in-degree slot capacity (deg ~ Poisson(10); P(>=64) ~ 1e-35)
static const int LBINS = 2048;   // nearest-neighbor tables: T1=1.5MB + T2=256KB -> L2-resident

__device__ __forceinline__ unsigned short f2bf(float f) {
    unsigned int u = __float_as_uint(f);
    unsigned int r = (u + 0x7FFFu + ((u >> 16) & 1u)) >> 16;   // RTN-even
    return (unsigned short)r;
}
__device__ __forceinline__ unsigned int packbf(float lo, float hi) {
    return (unsigned int)f2bf(lo) | ((unsigned int)f2bf(hi) << 16);
}
__device__ __forceinline__ float bflo(unsigned int u) { return __uint_as_float(u << 16); }
__device__ __forceinline__ float bfhi(unsigned int u) { return __uint_as_float(u & 0xFFFF0000u); }
__device__ __forceinline__ float bfu16(unsigned short u) { return __uint_as_float(((unsigned int)u) << 16); }

__device__ __forceinline__ void sph_l3(float x, float y, float z, float* sh) {
    const float s3   = 1.7320508075688772f;
    const float s5   = 2.23606797749979f;
    const float s7   = 2.6457513110645906f;
    const float s15  = 3.872983346207417f;
    const float s105 = 10.246950765959598f;
    const float c358 = 2.0916500663351889f;  // sqrt(35/8)
    const float c218 = 1.6201851746019651f;  // sqrt(21/8)
    float x2 = x * x, y2 = y * y, z2 = z * z;
    sh[0]  = 1.0f;
    sh[1]  = s3 * x;
    sh[2]  = s3 * y;
    sh[3]  = s3 * z;
    sh[4]  = s15 * x * z;
    sh[5]  = s15 * x * y;
    sh[6]  = 0.5f * s5 * (2.0f * y2 - x2 - z2);
    sh[7]  = s15 * y * z;
    sh[8]  = 0.5f * s15 * (z2 - x2);
    sh[9]  = c358 * x * (3.0f * z2 - x2);
    sh[10] = s105 * x * y * z;
    sh[11] = c218 * x * (4.0f * y2 - z2 - x2);
    sh[12] = 0.5f * s7 * y * (2.0f * y2 - 3.0f * z2 - 3.0f * x2);
    sh[13] = c218 * z * (4.0f * y2 - z2 - x2);
    sh[14] = 0.5f * s105 * y * (z2 - x2);
    sh[15] = c358 * z * (z2 - 3.0f * x2);
}

__device__ __forceinline__ void unpack16(uint4 a, uint4 b, float* s) {
    s[0] = bflo(a.x);  s[1] = bfhi(a.x);  s[2] = bflo(a.y);  s[3] = bfhi(a.y);
    s[4] = bflo(a.z);  s[5] = bfhi(a.z);  s[6] = bflo(a.w);  s[7] = bfhi(a.w);
    s[8] = bflo(b.x);  s[9] = bfhi(b.x);  s[10] = bflo(b.y); s[11] = bfhi(b.y);
    s[12] = bflo(b.z); s[13] = bfhi(b.z); s[14] = bflo(b.w); s[15] = bfhi(b.w);
}

template<int STR>
__device__ __forceinline__ void gemmB(const float* __restrict__ col,
                                      const float (*__restrict__ hs)[256], float* acc) {
#pragma unroll 8
    for (int cc = 0; cc < 256; ++cc) {
        float w = col[(size_t)cc * STR];
#pragma unroll
        for (int b = 0; b < BPB; ++b) acc[b] += hs[b][cc] * w;
    }
}

// ---------------- K0: build nearest-neighbor tables + zero cursor --------------------------
__global__ __launch_bounds__(256) void k_table(const float* __restrict__ W1a,
                                               const float* __restrict__ W1b,
                                               const float* __restrict__ W2a,
                                               const float* __restrict__ W2b,
                                               unsigned short* __restrict__ T1,
                                               unsigned short* __restrict__ T2, int lbins,
                                               int* __restrict__ cursor, int N) {
    __shared__ float h1s[BPB][256];
    __shared__ float h2s[BPB][256];
    const int c = threadIdx.x;
    const int bin0 = blockIdx.x * BPB;
    const int half = blockIdx.y;

    if (half == 0) {
        int zi = blockIdx.x * 256 + c;
        if (zi < N) cursor[zi] = 0;
    }

    const float inv_s3 = 0.57735026918962576f;
    const float bin2len = 4.0f / (float)(lbins - 1);
    float w1a0 = W1a[c], w1a1 = W1a[256 + c], w1a2 = W1a[512 + c];
    float w2a0 = W2a[c], w2a1 = W2a[256 + c], w2a2 = W2a[512 + c];
#pragma unroll
    for (int b = 0; b < BPB; ++b) {
        float len = (float)(bin0 + b) * bin2len;
        float d0 = len * 0.5f;
        float d1 = (len - 2.0f) * 0.5f;
        float d2 = (len - 4.0f) * 0.5f;
        float b0 = expf(-d0 * d0) * (1.0f / 1.12f);
        float b1 = expf(-d1 * d1) * (1.0f / 1.12f);
        float b2 = expf(-d2 * d2) * (1.0f / 1.12f);
        h1s[b][c] = fmaxf((b0 * w1a0 + b1 * w1a1 + b2 * w1a2) * inv_s3, 0.0f);
        if (half == 1)
            h2s[b][c] = fmaxf((b0 * w2a0 + b1 * w2a1 + b2 * w2a2) * inv_s3, 0.0f);
    }
    __syncthreads();

    float acc[BPB];
#pragma unroll
    for (int b = 0; b < BPB; ++b) acc[b] = 0.0f;
    int o = -1;  // output column in [0,448)
    if (half == 0) {
        if (c < 224) { o = c; gemmB<384>(W1b + o, h1s, acc); }
    } else {
        if (c < 64)       { o = 384 + c; gemmB<64>(W2b + c, h2s, acc); }
        else if (c < 224) { o = 160 + c; gemmB<384>(W1b + (160 + c), h1s, acc); }
    }
    if (o >= 0) {
        if (o < 384) {
            int k = o % 96, pp = o / 96;
#pragma unroll
            for (int b = 0; b < BPB; ++b) {
                int i = bin0 + b;
                T1[(((size_t)i * 96 + k) << 2) + pp] = f2bf(acc[b] * (1.0f / 16.0f));
            }
        } else {
            int k2 = o - 384;
#pragma unroll
            for (int b = 0; b < BPB; ++b) {
                int i = bin0 + b;
                T2[(size_t)i * 64 + k2] = f2bf(acc[b] * (1.0f / 16.0f));
            }
        }
    }
}

// ---------------- K1: scatter edges into per-dst slot buckets ------------------------------
__global__ void k_scatter(const float* __restrict__ evec, const float* __restrict__ elen,
                          const int* __restrict__ esrc, const int* __restrict__ edst,
                          int* __restrict__ cursor,
                          uint4* __restrict__ shB4, uint2* __restrict__ edgeSL,
                          int E, int lbins) {
    int e = blockIdx.x * blockDim.x + threadIdx.x;
    if (e >= E) return;
    int d = edst[e];
    int slotIdx = atomicAdd(&cursor[d], 1);
    if (slotIdx >= CAP) return;   // statistically never
    size_t pos = ((size_t)d << 6) + slotIdx;

    float vx = evec[3 * e], vy = evec[3 * e + 1], vz = evec[3 * e + 2];
    float nrm = sqrtf(vx * vx + vy * vy + vz * vz);
    float inv = 1.0f / (nrm + 1e-12f);
    float sh[16];
    sph_l3(vx * inv, vy * inv, vz * inv, sh);
    uint4 a, b;
    a.x = packbf(sh[0], sh[1]);  a.y = packbf(sh[2], sh[3]);
    a.z = packbf(sh[4], sh[5]);  a.w = packbf(sh[6], sh[7]);
    b.x = packbf(sh[8], sh[9]);  b.y = packbf(sh[10], sh[11]);
    b.z = packbf(sh[12], sh[13]); b.w = packbf(sh[14], sh[15]);
    shB4[pos * 2]     = a;
    shB4[pos * 2 + 1] = b;

    float len = elen[e];
    float p = fminf(fmaxf(len, 0.0f), 4.0f) * ((float)(lbins - 1) / 4.0f);
    int i0 = (int)(p + 0.5f);                  // nearest bin
    if (i0 > lbins - 1) i0 = lbins - 1;
    edgeSL[pos] = make_uint2((unsigned int)esrc[e], (unsigned int)i0);
}

// ---------------- K2: x[n][16] = inv_nn * sum of node's slot rows (thread per node) --------
__global__ void k_x(const uint4* __restrict__ shB4, const int* __restrict__ cursor,
                    float4* __restrict__ x4, int N) {
    int n = blockIdx.x * blockDim.x + threadIdx.x;
    if (n >= N) return;
    float acc[16];
#pragma unroll
    for (int i = 0; i < 16; ++i) acc[i] = 0.0f;
    int cnt = min(cursor[n], CAP);
    size_t base = (size_t)n << 6;
#pragma unroll 4
    for (int j = 0; j < cnt; ++j) {
        uint4 a = shB4[(base + j) * 2], b = shB4[(base + j) * 2 + 1];
        float s[16];
        unpack16(a, b, s);
#pragma unroll
        for (int i = 0; i < 16; ++i) acc[i] += s[i];
    }
    const float inv_nn = 0.51298917604257706f;
    float4* xp = x4 + (size_t)n * 4;
    xp[0] = make_float4(acc[0] * inv_nn, acc[1] * inv_nn, acc[2] * inv_nn, acc[3] * inv_nn);
    xp[1] = make_float4(acc[4] * inv_nn, acc[5] * inv_nn, acc[6] * inv_nn, acc[7] * inv_nn);
    xp[2] = make_float4(acc[8] * inv_nn, acc[9] * inv_nn, acc[10] * inv_nn, acc[11] * inv_nn);
    xp[3] = make_float4(acc[12] * inv_nn, acc[13] * inv_nn, acc[14] * inv_nn, acc[15] * inv_nn);
}

// ---------------- K3: fused dots + h[96] + activations -> y  (2 nodes per 192-thread block) -
__global__ __launch_bounds__(192) void k_hy(const uint4* __restrict__ shB4,
                                            const uint2* __restrict__ edgeSL,
                                            const int* __restrict__ cursor,
                                            const float4* __restrict__ x4,
                                            const uint2* __restrict__ T1v,
                                            float* __restrict__ y, int N) {
    const int t = threadIdx.x;
    const int n0 = blockIdx.x * 2;
    __shared__ float4 sdots[2][CAP];
    __shared__ int sbin[2][CAP];
    __shared__ float hs[2][96];
    const float rs3 = 0.57735026918962576f;
    const float rs5 = 0.44721359549995793f;
    const float rs7 = 0.37796447300922720f;

    // ---- staging: threads 0..127; lane group (t>>6) stages node n0 + (t>>6), slot t&63 ----
    if (t < 128) {
        int which = t >> 6;
        int nn = n0 + which;
        if (nn < N) {
            int cnt = min(cursor[nn], CAP);
            int slot = t & 63;
            if (slot < cnt) {
                size_t j = ((size_t)nn << 6) + slot;
                uint2 sl = edgeSL[j];
                uint4 a = shB4[j * 2], b = shB4[j * 2 + 1];
                float s[16];
                unpack16(a, b, s);
                const float4* xr = x4 + (size_t)sl.x * 4;
                float4 x0 = xr[0], x1 = xr[1], x2 = xr[2], x3 = xr[3];
                float d0 = x0.x * s[0];
                float d1 = x0.y * s[1] + x0.z * s[2] + x0.w * s[3];
                float d2 = x1.x * s[4] + x1.y * s[5] + x1.z * s[6] + x1.w * s[7] + x2.x * s[8];
                float d3 = x2.y * s[9] + x2.z * s[10] + x2.w * s[11]
                         + x3.x * s[12] + x3.y * s[13] + x3.z * s[14] + x3.w * s[15];
                sdots[which][slot] = make_float4(d0, d1 * rs3, d2 * rs5, d3 * rs7);
                sbin[which][slot] = (int)sl.y;
            }
        }
    }
    __syncthreads();

    // ---- compute h[96]: t in [0,96) -> node n0, t in [96,192) -> node n0+1 ----
    {
        int which = (t >= 96) ? 1 : 0;
        int kk = t - which * 96;
        int nn = n0 + which;
        if (nn < N) {
            int cnt = min(cursor[nn], CAP);
            float acc = 0.0f;
#pragma unroll 4
            for (int q = 0; q < cnt; ++q) {
                float4 dt = sdots[which][q];
                int i0 = sbin[which][q];
                uint2 u = T1v[(size_t)i0 * 96 + kk];
                acc += dt.x * bflo(u.x) + dt.y * bfhi(u.x)
                     + dt.z * bflo(u.y) + dt.w * bfhi(u.y);
            }
            const float scale = 0.25649458802128853f;  // 0.5 * inv_nn
            hs[which][kk] = acc * scale;
        }
    }
    __syncthreads();

    // ---- activation + store: t<64 -> node n0; 96<=t<160 -> node n0+1 ----
    {
        int which = (t >= 96) ? 1 : 0;
        int tt = t - which * 96;
        int nn = n0 + which;
        if (tt < 64 && nn < N) {
            float outv;
            if (tt < 32) {
                float v = hs[which][tt];
                outv = (tt < 16) ? fmaxf(v, 0.0f) : fabsf(v);
            } else {
                int kg = tt - 32;
                float g = hs[which][32 + kg];
                float vv = hs[which][64 + kg];
                float ga = (kg < 8 || (kg >= 16 && kg < 24)) ? fmaxf(g, 0.0f) : tanhf(g);
                outv = ga * vv;
            }
            y[(size_t)nn * 64 + tt] = outv;
        }
    }
}

// ---------------- K4: out[n] = inv_nn/8 * sum_j y[src_j]·w2(bin_j)  (wave/node) -------------
__global__ void k_out(const uint2* __restrict__ edgeSL, const int* __restrict__ cursor,
                      const float* __restrict__ y,
                      const unsigned short* __restrict__ T2, float* __restrict__ out, int N) {
    int n = (blockIdx.x * blockDim.x + threadIdx.x) >> 6;
    int lane = threadIdx.x & 63;
    if (n >= N) return;
    int cnt = min(cursor[n], CAP);
    size_t base = (size_t)n << 6;
    float acc = 0.0f;
#pragma unroll 4
    for (int j = 0; j < cnt; ++j) {
        uint2 sl = edgeSL[base + j];
        float w2v = bfu16(T2[(size_t)sl.y * 64 + lane]);
        acc += y[(size_t)sl.x * 64 + lane] * w2v;
    }
#pragma unroll
    for (int off = 32; off > 0; off >>= 1) acc += __shfl_xor(acc, off, 64);
    if (lane == 0) out[n] = acc * (0.51298917604257706f / 8.0f);
}

extern "C" void kernel_launch(void* const* d_in, const int* in_sizes, int n_in,
                              void* d_out, int out_size, void* d_ws, size_t ws_size,
                              hipStream_t stream) {
    const float* evec = (const float*)d_in[0];
    const float* elen = (const float*)d_in[1];
    const float* W1a  = (const float*)d_in[2];
    const float* W1b  = (const float*)d_in[3];
    const float* W2a  = (const float*)d_in[4];
    const float* W2b  = (const float*)d_in[5];
    const int* esrc   = (const int*)d_in[6];
    const int* edst   = (const int*)d_in[7];
    const int E = in_sizes[1];
    const int N = out_size;
    float* out = (float*)d_out;

    char* ws = (char*)d_ws;
    size_t off = 0;
    auto alloc = [&](size_t bytes) -> void* {
        void* p = ws + off;
        off = (off + bytes + 255) & ~(size_t)255;
        return p;
    };

    int*    cursor = (int*)alloc((size_t)N * 4);
    uint4*  shB4   = (uint4*)alloc((size_t)N * CAP * 32);
    uint2*  edgeSL = (uint2*)alloc((size_t)N * CAP * 8);
    float4* x4     = (float4*)alloc((size_t)N * 64);
    float*  y      = (float*)alloc((size_t)N * 64 * 4);

    int lbins = LBINS;
    if (ws_size > off) {
        size_t avail = ws_size - off;
        size_t maxbins = avail / (96 * 8 + 64 * 2);   // bytes per bin: T1 + T2 (nearest)
        if ((size_t)lbins > maxbins) lbins = (int)((maxbins / BPB) * BPB);
    }
    if (lbins < 2 * BPB) lbins = 2 * BPB;
    unsigned short* T1 = (unsigned short*)alloc((size_t)lbins * 96 * 8);
    unsigned short* T2 = (unsigned short*)alloc((size_t)lbins * 64 * 2);

    k_table<<<dim3(lbins / BPB, 2), 256, 0, stream>>>(W1a, W1b, W2a, W2b, T1, T2, lbins,
                                                      cursor, N);
    k_scatter<<<(E + 255) / 256, 256, 0, stream>>>(evec, elen, esrc, edst, cursor,
                                                   shB4, edgeSL, E, lbins);
    k_x<<<(N + 255) / 256, 256, 0, stream>>>(shB4, cursor, x4, N);
    k_hy<<<(N + 1) / 2, 192, 0, stream>>>(shB4, edgeSL, cursor, x4, (const uint2*)T1, y, N);
    {
        long long threads = (long long)N * 64;
        int blocks = (int)((threads + 255) / 256);
        k_out<<<blocks, 256, 0, stream>>>(edgeSL, cursor, y, T2, out, N);
    }
}